// Round 1
// baseline (741.003 us; speedup 1.0000x reference)
//
#include <hip/hip_runtime.h>
#include <math.h>

// Problem constants (B=4, N=1024, D=1024, H=2048, E=8)
#define T_TOK 4096
#define DIM   1024
#define HID   2048
#define NE    8
#define TT    64   // token tile / col tile
#define KB    16   // k-chunk

__device__ __forceinline__ float gelu_exact(float v) {
    // jax.nn.gelu(x, approximate=False) = 0.5*x*(1+erf(x/sqrt(2)))
    return 0.5f * v * (1.0f + erff(v * 0.70710678118654752440f));
}

// ---------------------------------------------------------------------------
// Gate: logits = x @ gate_w + gate_b ; softmax ; top-1 ; importance sums
// One wave (64 lanes) per token; block = 256 = 4 tokens.
// ---------------------------------------------------------------------------
__global__ __launch_bounds__(256) void gate_kernel(
    const float* __restrict__ x, const float* __restrict__ gw,
    const float* __restrict__ gb, float* __restrict__ top_val,
    int* __restrict__ top_idx, float* __restrict__ importance,
    int* __restrict__ counts)
{
    __shared__ float s_imp[NE];
    __shared__ int   s_cnt[NE];
    if (threadIdx.x < NE) { s_imp[threadIdx.x] = 0.f; s_cnt[threadIdx.x] = 0; }
    __syncthreads();

    const int wave = threadIdx.x >> 6;
    const int lane = threadIdx.x & 63;
    const int t = blockIdx.x * 4 + wave;

    float acc[NE];
    #pragma unroll
    for (int e = 0; e < NE; e++) acc[e] = 0.f;

    const float* xr = x + (size_t)t * DIM;
    #pragma unroll 4
    for (int k = lane; k < DIM; k += 64) {
        float xv = xr[k];
        const float* g = gw + (size_t)k * NE;
        float4 g0 = *(const float4*)g;
        float4 g1 = *(const float4*)(g + 4);
        acc[0] += xv * g0.x; acc[1] += xv * g0.y;
        acc[2] += xv * g0.z; acc[3] += xv * g0.w;
        acc[4] += xv * g1.x; acc[5] += xv * g1.y;
        acc[6] += xv * g1.z; acc[7] += xv * g1.w;
    }
    #pragma unroll
    for (int e = 0; e < NE; e++) {
        #pragma unroll
        for (int off = 32; off > 0; off >>= 1)
            acc[e] += __shfl_down(acc[e], off, 64);
    }
    if (lane == 0) {
        float l[NE];
        float m = -1e30f;
        #pragma unroll
        for (int e = 0; e < NE; e++) { l[e] = acc[e] + gb[e]; m = fmaxf(m, l[e]); }
        float s = 0.f;
        #pragma unroll
        for (int e = 0; e < NE; e++) { l[e] = expf(l[e] - m); s += l[e]; }
        float inv = 1.f / s;
        int bi = 0; float bv = -1.f;
        #pragma unroll
        for (int e = 0; e < NE; e++) {
            float p = l[e] * inv;
            atomicAdd(&s_imp[e], p);
            if (p > bv) { bv = p; bi = e; }   // strict > => first-occurrence argmax
        }
        top_val[t] = bv;
        top_idx[t] = bi;
        atomicAdd(&s_cnt[bi], 1);
    }
    __syncthreads();
    if (threadIdx.x < NE) {
        atomicAdd(&importance[threadIdx.x], s_imp[threadIdx.x]);
        atomicAdd(&counts[threadIdx.x],     s_cnt[threadIdx.x]);
    }
}

// ---------------------------------------------------------------------------
// Plan: expert offsets, tile table, load-balance loss. Single thread (E=8).
// ---------------------------------------------------------------------------
__global__ void plan_kernel(const int* __restrict__ counts,
                            const float* __restrict__ importance,
                            int* __restrict__ offsets, int* __restrict__ tile_e,
                            int* __restrict__ tile_s, int* __restrict__ tile_rows,
                            int* __restrict__ ntiles, float* __restrict__ loss_out)
{
    if (threadIdx.x == 0 && blockIdx.x == 0) {
        int off = 0, nt = 0;
        for (int e = 0; e < NE; e++) {
            offsets[e] = off;
            int c = counts[e];
            for (int s = 0; s < c; s += TT) {
                tile_e[nt] = e;
                tile_s[nt] = off + s;
                tile_rows[nt] = min(TT, c - s);
                nt++;
            }
            off += c;
        }
        offsets[NE] = off;
        *ntiles = nt;

        float mean = 0.f;
        for (int e = 0; e < NE; e++) mean += importance[e];
        mean *= (1.0f / NE);
        float var = 0.f;
        for (int e = 0; e < NE; e++) { float d = importance[e] - mean; var += d * d; }
        var *= (1.0f / (NE - 1));
        loss_out[0] = var / (mean * mean + 1e-10f);
    }
}

// ---------------------------------------------------------------------------
// Scatter: sorted token list per expert.
// ---------------------------------------------------------------------------
__global__ void scatter_kernel(const int* __restrict__ top_idx,
                               const int* __restrict__ offsets,
                               int* __restrict__ cursors,
                               int* __restrict__ sorted_tok)
{
    int t = blockIdx.x * blockDim.x + threadIdx.x;
    if (t < T_TOK) {
        int e = top_idx[t];
        int pos = atomicAdd(&cursors[e], 1);
        sorted_tok[offsets[e] + pos] = t;
    }
}

// ---------------------------------------------------------------------------
// FFN layer 1: h = gelu(Xgathered @ w1[e] + b1[e])  -> h_buf (sorted order)
// 64x64 tile, 256 threads, 4x4 micro-tile, KB=16 LDS chunks.
// ---------------------------------------------------------------------------
__global__ __launch_bounds__(256) void ffn1_kernel(
    const float* __restrict__ x, const float* __restrict__ w1,
    const float* __restrict__ b1, const int* __restrict__ sorted_tok,
    const int* __restrict__ tile_e, const int* __restrict__ tile_s,
    const int* __restrict__ tile_rows, const int* __restrict__ ntiles,
    float* __restrict__ h_buf)
{
    const int tile = blockIdx.x;
    if (tile >= *ntiles) return;
    const int e     = tile_e[tile];
    const int sbase = tile_s[tile];
    const int rows  = tile_rows[tile];
    const int hbase = blockIdx.y * TT;

    __shared__ float Xs[KB][TT + 4];
    __shared__ float Ws[KB][TT + 4];

    const int th = threadIdx.x;
    const int ty = th >> 4, tx = th & 15;

    // A-tile load mapping: thread -> (token row a_tt, 4 consecutive k at a_kq)
    const int a_tt = th >> 2;
    const int a_kq = (th & 3) * 4;
    const float* aptr = nullptr;
    if (a_tt < rows) {
        int tok = sorted_tok[sbase + a_tt];
        aptr = x + (size_t)tok * DIM + a_kq;
    }
    // B-tile load mapping: thread -> (k row b_kk, 4 consecutive h at b_hq)
    const int b_kk = th >> 4;
    const int b_hq = (th & 15) * 4;
    const float* bptr = w1 + ((size_t)e * DIM + b_kk) * HID + hbase + b_hq;

    float acc[4][4];
    #pragma unroll
    for (int i = 0; i < 4; i++)
        #pragma unroll
        for (int j = 0; j < 4; j++) acc[i][j] = 0.f;

    for (int k0 = 0; k0 < DIM; k0 += KB) {
        float4 av = make_float4(0.f, 0.f, 0.f, 0.f);
        if (aptr) av = *(const float4*)(aptr + k0);
        float4 bv = *(const float4*)(bptr + (size_t)k0 * HID);
        __syncthreads();
        Xs[a_kq + 0][a_tt] = av.x;
        Xs[a_kq + 1][a_tt] = av.y;
        Xs[a_kq + 2][a_tt] = av.z;
        Xs[a_kq + 3][a_tt] = av.w;
        *(float4*)&Ws[b_kk][b_hq] = bv;
        __syncthreads();
        #pragma unroll
        for (int kk = 0; kk < KB; kk++) {
            float4 a4 = *(const float4*)&Xs[kk][ty * 4];
            float4 b4 = *(const float4*)&Ws[kk][tx * 4];
            float a[4] = {a4.x, a4.y, a4.z, a4.w};
            float b[4] = {b4.x, b4.y, b4.z, b4.w};
            #pragma unroll
            for (int i = 0; i < 4; i++)
                #pragma unroll
                for (int j = 0; j < 4; j++)
                    acc[i][j] = fmaf(a[i], b[j], acc[i][j]);
        }
    }

    float4 bias = *(const float4*)&b1[(size_t)e * HID + hbase + tx * 4];
    #pragma unroll
    for (int i = 0; i < 4; i++) {
        int tt = ty * 4 + i;
        if (tt < rows) {
            size_t off = (size_t)(sbase + tt) * HID + hbase + tx * 4;
            float4 o;
            o.x = gelu_exact(acc[i][0] + bias.x);
            o.y = gelu_exact(acc[i][1] + bias.y);
            o.z = gelu_exact(acc[i][2] + bias.z);
            o.w = gelu_exact(acc[i][3] + bias.w);
            *(float4*)&h_buf[off] = o;
        }
    }
}

// ---------------------------------------------------------------------------
// FFN layer 2: y_pre = x + (h @ w2[e] + b2[e]) * top_val   -> d_out (token order)
// ---------------------------------------------------------------------------
__global__ __launch_bounds__(256) void ffn2_kernel(
    const float* __restrict__ x, const float* __restrict__ w2,
    const float* __restrict__ b2, const float* __restrict__ h_buf,
    const int* __restrict__ sorted_tok, const float* __restrict__ top_val,
    const int* __restrict__ tile_e, const int* __restrict__ tile_s,
    const int* __restrict__ tile_rows, const int* __restrict__ ntiles,
    float* __restrict__ yout)
{
    const int tile = blockIdx.x;
    if (tile >= *ntiles) return;
    const int e     = tile_e[tile];
    const int sbase = tile_s[tile];
    const int rows  = tile_rows[tile];
    const int dbase = blockIdx.y * TT;

    __shared__ float Hs[KB][TT + 4];
    __shared__ float Ws[KB][TT + 4];

    const int th = threadIdx.x;
    const int ty = th >> 4, tx = th & 15;

    const int a_tt = th >> 2;
    const int a_kq = (th & 3) * 4;
    const float* aptr = nullptr;
    if (a_tt < rows) aptr = h_buf + (size_t)(sbase + a_tt) * HID + a_kq;

    const int b_kk = th >> 4;
    const int b_dq = (th & 15) * 4;
    const float* bptr = w2 + ((size_t)e * HID + b_kk) * DIM + dbase + b_dq;

    float acc[4][4];
    #pragma unroll
    for (int i = 0; i < 4; i++)
        #pragma unroll
        for (int j = 0; j < 4; j++) acc[i][j] = 0.f;

    for (int k0 = 0; k0 < HID; k0 += KB) {
        float4 av = make_float4(0.f, 0.f, 0.f, 0.f);
        if (aptr) av = *(const float4*)(aptr + k0);
        float4 bv = *(const float4*)(bptr + (size_t)k0 * DIM);
        __syncthreads();
        Hs[a_kq + 0][a_tt] = av.x;
        Hs[a_kq + 1][a_tt] = av.y;
        Hs[a_kq + 2][a_tt] = av.z;
        Hs[a_kq + 3][a_tt] = av.w;
        *(float4*)&Ws[b_kk][b_dq] = bv;
        __syncthreads();
        #pragma unroll
        for (int kk = 0; kk < KB; kk++) {
            float4 a4 = *(const float4*)&Hs[kk][ty * 4];
            float4 b4 = *(const float4*)&Ws[kk][tx * 4];
            float a[4] = {a4.x, a4.y, a4.z, a4.w};
            float b[4] = {b4.x, b4.y, b4.z, b4.w};
            #pragma unroll
            for (int i = 0; i < 4; i++)
                #pragma unroll
                for (int j = 0; j < 4; j++)
                    acc[i][j] = fmaf(a[i], b[j], acc[i][j]);
        }
    }

    float4 bias = *(const float4*)&b2[(size_t)e * DIM + dbase + tx * 4];
    #pragma unroll
    for (int i = 0; i < 4; i++) {
        int tt = ty * 4 + i;
        if (tt < rows) {
            int t = sorted_tok[sbase + tt];
            float tv = top_val[t];
            size_t off = (size_t)t * DIM + dbase + tx * 4;
            float4 xv = *(const float4*)&x[off];
            float4 o;
            o.x = xv.x + (acc[i][0] + bias.x) * tv;
            o.y = xv.y + (acc[i][1] + bias.y) * tv;
            o.z = xv.z + (acc[i][2] + bias.z) * tv;
            o.w = xv.w + (acc[i][3] + bias.w) * tv;
            *(float4*)&yout[off] = o;
        }
    }
}

// ---------------------------------------------------------------------------
// RMSNorm (F.normalize * gamma * sqrt(D)) + exact GeLU, in place on d_out.
// One block (256 threads) per token row; float4 per thread.
// ---------------------------------------------------------------------------
__global__ __launch_bounds__(256) void norm_kernel(float* __restrict__ y,
                                                   const float* __restrict__ gamma)
{
    const int t = blockIdx.x;
    float* row = y + (size_t)t * DIM;
    const int th = threadIdx.x;
    float4 v = *(const float4*)&row[th * 4];
    float ss = v.x * v.x + v.y * v.y + v.z * v.z + v.w * v.w;

    const int lane = th & 63, wave = th >> 6;
    #pragma unroll
    for (int off = 32; off > 0; off >>= 1) ss += __shfl_down(ss, off, 64);
    __shared__ float red[4];
    if (lane == 0) red[wave] = ss;
    __syncthreads();
    float total = red[0] + red[1] + red[2] + red[3];

    float nrm = sqrtf(total);
    float scale = 32.0f / fmaxf(nrm, 1e-12f);   // sqrt(1024) = 32

    float4 g = *(const float4*)&gamma[th * 4];
    float4 o;
    o.x = gelu_exact(v.x * scale * g.x);
    o.y = gelu_exact(v.y * scale * g.y);
    o.z = gelu_exact(v.z * scale * g.z);
    o.w = gelu_exact(v.w * scale * g.w);
    *(float4*)&row[th * 4] = o;
}

// ---------------------------------------------------------------------------
extern "C" void kernel_launch(void* const* d_in, const int* in_sizes, int n_in,
                              void* d_out, int out_size, void* d_ws, size_t ws_size,
                              hipStream_t stream) {
    const float* x      = (const float*)d_in[0];
    const float* gate_w = (const float*)d_in[1];
    const float* gate_b = (const float*)d_in[2];
    const float* w1     = (const float*)d_in[3];
    const float* b1     = (const float*)d_in[4];
    const float* w2     = (const float*)d_in[5];
    const float* b2     = (const float*)d_in[6];
    const float* gamma  = (const float*)d_in[7];

    float* out  = (float*)d_out;                      // [T*D] y, then [1] loss
    float* loss = out + (size_t)T_TOK * DIM;

    char* ws = (char*)d_ws;
    float* top_val    = (float*)(ws + 0);        // 4096 f
    int*   top_idx    = (int*)  (ws + 16384);    // 4096 i
    int*   sorted_tok = (int*)  (ws + 32768);    // 4096 i
    float* importance = (float*)(ws + 49152);    // 8 f   (zeroed)
    int*   counts     = (int*)  (ws + 49184);    // 8 i   (zeroed)
    int*   cursors    = (int*)  (ws + 49216);    // 8 i   (zeroed)
    int*   offsets    = (int*)  (ws + 49248);    // 9 i
    int*   tile_e     = (int*)  (ws + 49536);    // 72 i
    int*   tile_s     = (int*)  (ws + 49824);    // 72 i
    int*   tile_rows  = (int*)  (ws + 50112);    // 72 i
    int*   ntiles     = (int*)  (ws + 50400);    // 1 i
    float* h_buf      = (float*)(ws + 65536);    // 4096*2048 f = 32 MiB

    // zero the accumulator control block (ws is poisoned 0xAA each call)
    hipMemsetAsync(ws + 49152, 0, 96, stream);

    gate_kernel<<<T_TOK / 4, 256, 0, stream>>>(x, gate_w, gate_b, top_val,
                                               top_idx, importance, counts);
    plan_kernel<<<1, 64, 0, stream>>>(counts, importance, offsets, tile_e,
                                      tile_s, tile_rows, ntiles, loss);
    scatter_kernel<<<T_TOK / 256, 256, 0, stream>>>(top_idx, offsets, cursors,
                                                    sorted_tok);
    // max tiles = sum ceil(c_e/64) <= 4096/64 + 8 = 72
    ffn1_kernel<<<dim3(72, HID / TT), 256, 0, stream>>>(
        x, w1, b1, sorted_tok, tile_e, tile_s, tile_rows, ntiles, h_buf);
    ffn2_kernel<<<dim3(72, DIM / TT), 256, 0, stream>>>(
        x, w2, b2, h_buf, sorted_tok, top_val, tile_e, tile_s, tile_rows,
        ntiles, out);
    norm_kernel<<<T_TOK, 256, 0, stream>>>(out, gamma);
}

// Round 2
// 383.541 us; speedup vs baseline: 1.9320x; 1.9320x over previous
//
#include <hip/hip_runtime.h>
#include <math.h>

// Problem constants (B=4, N=1024, D=1024, H=2048, E=8)
#define T_TOK 4096
#define DIM   1024
#define HID   2048
#define NE    8
#define TM    128   // M/N tile for MFMA GEMMs
#define BK    64    // K chunk (bf16)

typedef unsigned int  u32;
typedef unsigned short u16;
typedef __attribute__((ext_vector_type(8))) short bf16x8;  // 8 bf16 in 4 VGPRs
typedef __attribute__((ext_vector_type(4))) float f32x4;

__device__ __forceinline__ float gelu_exact(float v) {
    return 0.5f * v * (1.0f + erff(v * 0.70710678118654752440f));
}

__device__ __forceinline__ u16 f2bf(float v) {
    u32 u = __float_as_uint(v);
    u32 r = (u + 0x7FFFu + ((u >> 16) & 1u)) >> 16;   // RNE
    return (u16)r;
}

// async global->LDS, 16B per lane; lds dest = wave-uniform base + lane*16
__device__ __forceinline__ void gld_lds16(const void* g, void* l) {
    __builtin_amdgcn_global_load_lds(
        (const __attribute__((address_space(1))) u32*)g,
        (__attribute__((address_space(3))) u32*)l,
        16, 0, 0);
}

// ---------------------------------------------------------------------------
// Gate: logits = x @ gate_w + gate_b ; softmax ; top-1 ; importance sums
// ---------------------------------------------------------------------------
__global__ __launch_bounds__(256) void gate_kernel(
    const float* __restrict__ x, const float* __restrict__ gw,
    const float* __restrict__ gb, float* __restrict__ top_val,
    int* __restrict__ top_idx, float* __restrict__ importance,
    int* __restrict__ counts)
{
    __shared__ float s_imp[NE];
    __shared__ int   s_cnt[NE];
    if (threadIdx.x < NE) { s_imp[threadIdx.x] = 0.f; s_cnt[threadIdx.x] = 0; }
    __syncthreads();

    const int wave = threadIdx.x >> 6;
    const int lane = threadIdx.x & 63;
    const int t = blockIdx.x * 4 + wave;

    float acc[NE];
    #pragma unroll
    for (int e = 0; e < NE; e++) acc[e] = 0.f;

    const float* xr = x + (size_t)t * DIM;
    #pragma unroll 4
    for (int k = lane; k < DIM; k += 64) {
        float xv = xr[k];
        const float* g = gw + (size_t)k * NE;
        float4 g0 = *(const float4*)g;
        float4 g1 = *(const float4*)(g + 4);
        acc[0] += xv * g0.x; acc[1] += xv * g0.y;
        acc[2] += xv * g0.z; acc[3] += xv * g0.w;
        acc[4] += xv * g1.x; acc[5] += xv * g1.y;
        acc[6] += xv * g1.z; acc[7] += xv * g1.w;
    }
    #pragma unroll
    for (int e = 0; e < NE; e++) {
        #pragma unroll
        for (int off = 32; off > 0; off >>= 1)
            acc[e] += __shfl_down(acc[e], off, 64);
    }
    if (lane == 0) {
        float l[NE];
        float m = -1e30f;
        #pragma unroll
        for (int e = 0; e < NE; e++) { l[e] = acc[e] + gb[e]; m = fmaxf(m, l[e]); }
        float s = 0.f;
        #pragma unroll
        for (int e = 0; e < NE; e++) { l[e] = expf(l[e] - m); s += l[e]; }
        float inv = 1.f / s;
        int bi = 0; float bv = -1.f;
        #pragma unroll
        for (int e = 0; e < NE; e++) {
            float p = l[e] * inv;
            atomicAdd(&s_imp[e], p);
            if (p > bv) { bv = p; bi = e; }
        }
        top_val[t] = bv;
        top_idx[t] = bi;
        atomicAdd(&s_cnt[bi], 1);
    }
    __syncthreads();
    if (threadIdx.x < NE) {
        atomicAdd(&importance[threadIdx.x], s_imp[threadIdx.x]);
        atomicAdd(&counts[threadIdx.x],     s_cnt[threadIdx.x]);
    }
}

// ---------------------------------------------------------------------------
// Plan: expert offsets, 128-row tile table, load-balance loss.
// ---------------------------------------------------------------------------
__global__ void plan_kernel(const int* __restrict__ counts,
                            const float* __restrict__ importance,
                            int* __restrict__ offsets, int* __restrict__ tile_e,
                            int* __restrict__ tile_s, int* __restrict__ tile_rows,
                            int* __restrict__ ntiles, float* __restrict__ loss_out)
{
    if (threadIdx.x == 0 && blockIdx.x == 0) {
        int off = 0, nt = 0;
        for (int e = 0; e < NE; e++) {
            offsets[e] = off;
            int c = counts[e];
            for (int s = 0; s < c; s += TM) {
                tile_e[nt] = e;
                tile_s[nt] = off + s;
                tile_rows[nt] = min(TM, c - s);
                nt++;
            }
            off += c;
        }
        offsets[NE] = off;
        *ntiles = nt;   // <= 4096/128 + 8 = 40

        float mean = 0.f;
        for (int e = 0; e < NE; e++) mean += importance[e];
        mean *= (1.0f / NE);
        float var = 0.f;
        for (int e = 0; e < NE; e++) { float d = importance[e] - mean; var += d * d; }
        var *= (1.0f / (NE - 1));
        loss_out[0] = var / (mean * mean + 1e-10f);
    }
}

// ---------------------------------------------------------------------------
// Scatter: sorted token list per expert.
// ---------------------------------------------------------------------------
__global__ void scatter_kernel(const int* __restrict__ top_idx,
                               const int* __restrict__ offsets,
                               int* __restrict__ cursors,
                               int* __restrict__ sorted_tok)
{
    int t = blockIdx.x * blockDim.x + threadIdx.x;
    if (t < T_TOK) {
        int e = top_idx[t];
        int pos = atomicAdd(&cursors[e], 1);
        sorted_tok[offsets[e] + pos] = t;
    }
}

// ---------------------------------------------------------------------------
// Gather x rows into sorted order, fp32 -> bf16. One block per sorted row.
// ---------------------------------------------------------------------------
__global__ __launch_bounds__(256) void gather_x_kernel(
    const float* __restrict__ x, const int* __restrict__ sorted_tok,
    u16* __restrict__ xs)
{
    const int s = blockIdx.x;
    const int tok = sorted_tok[s];
    const float* src = x + (size_t)tok * DIM;
    u16* dst = xs + (size_t)s * DIM;
    const int i = threadIdx.x * 4;
    float4 v = *(const float4*)&src[i];
    ushort4 o;
    o.x = f2bf(v.x); o.y = f2bf(v.y); o.z = f2bf(v.z); o.w = f2bf(v.w);
    *(ushort4*)&dst[i] = o;
}

// ---------------------------------------------------------------------------
// Transpose + convert: in [E][R][C] f32  ->  out [E][C][R] bf16
// grid (C/32, R/32, E), block 256.
// ---------------------------------------------------------------------------
__global__ __launch_bounds__(256) void transpose_bf16_kernel(
    const float* __restrict__ in, u16* __restrict__ out, int R, int C)
{
    __shared__ float tile[32][33];
    const float* src = in  + (size_t)blockIdx.z * R * C;
    u16*         dst = out + (size_t)blockIdx.z * R * C;
    const int c0 = blockIdx.x * 32, r0 = blockIdx.y * 32;
    const int tc = threadIdx.x & 31, tr = threadIdx.x >> 5;  // tr in 0..7
    #pragma unroll
    for (int i = 0; i < 4; i++) {
        int r = tr + i * 8;
        tile[r][tc] = src[(size_t)(r0 + r) * C + c0 + tc];
    }
    __syncthreads();
    #pragma unroll
    for (int i = 0; i < 4; i++) {
        int cc = tr + i * 8;      // output row = c0+cc
        float v = tile[tc][cc];   // stride-33 read: conflict-free
        dst[(size_t)(c0 + cc) * R + r0 + tc] = f2bf(v);
    }
}

// ---------------------------------------------------------------------------
// FFN1 (MFMA): h = gelu(Xs @ W1t^T + b1) in sorted order, bf16 out.
// Xs: [4096][DIM] bf16 (sorted). W1t: [E][HID][DIM] bf16. h: [4096][HID] bf16.
// ---------------------------------------------------------------------------
__global__ __launch_bounds__(256) void ffn1_mfma(
    const u16* __restrict__ xs, const u16* __restrict__ w1t,
    const float* __restrict__ b1,
    const int* __restrict__ tile_e, const int* __restrict__ tile_s,
    const int* __restrict__ tile_rows, const int* __restrict__ ntiles,
    u16* __restrict__ h_buf)
{
    const int tile = blockIdx.x;
    if (tile >= *ntiles) return;
    const int e     = tile_e[tile];
    const int sbase = tile_s[tile];
    const int rows  = tile_rows[tile];
    const int nbase = blockIdx.y * TM;    // over HID

    __shared__ __align__(16) u16 As[TM * BK];
    __shared__ __align__(16) u16 Bs[TM * BK];

    const int th = threadIdx.x;
    const int w  = th >> 6;
    const int l  = th & 63;
    const int wm = w >> 1, wn = w & 1;
    const int lr = l >> 3;          // row within 8-row group
    const int lc = (l & 7) * 8;     // ushort offset within row (16B chunks)

    f32x4 acc[4][4] = {};

    const u16* wbase = w1t + (size_t)e * HID * DIM + (size_t)nbase * DIM;

    for (int k0 = 0; k0 < DIM; k0 += BK) {
        __syncthreads();
        #pragma unroll
        for (int c = 0; c < 4; c++) {
            const int r = w * 32 + c * 8;
            int srow = sbase + r + lr; if (srow > T_TOK - 1) srow = T_TOK - 1;
            gld_lds16(xs + (size_t)srow * DIM + k0 + lc, &As[r * BK]);
        }
        #pragma unroll
        for (int c = 0; c < 4; c++) {
            const int r = w * 32 + c * 8;
            gld_lds16(wbase + (size_t)(r + lr) * DIM + k0 + lc, &Bs[r * BK]);
        }
        __syncthreads();
        #pragma unroll
        for (int ks = 0; ks < 2; ks++) {
            const int ko = ks * 32 + (l >> 4) * 8;
            bf16x8 af[4], bfr[4];
            #pragma unroll
            for (int i = 0; i < 4; i++) {
                af[i]  = *(const bf16x8*)&As[(wm * 64 + i * 16 + (l & 15)) * BK + ko];
                bfr[i] = *(const bf16x8*)&Bs[(wn * 64 + i * 16 + (l & 15)) * BK + ko];
            }
            #pragma unroll
            for (int mi = 0; mi < 4; mi++)
                #pragma unroll
                for (int ni = 0; ni < 4; ni++)
                    acc[mi][ni] = __builtin_amdgcn_mfma_f32_16x16x32_bf16(
                        af[mi], bfr[ni], acc[mi][ni], 0, 0, 0);
        }
    }

    const int col = l & 15, quad = l >> 4;
    #pragma unroll
    for (int ni = 0; ni < 4; ni++) {
        const int n = nbase + wn * 64 + ni * 16 + col;
        const float bias = b1[e * HID + n];
        #pragma unroll
        for (int mi = 0; mi < 4; mi++) {
            #pragma unroll
            for (int r = 0; r < 4; r++) {
                const int m = wm * 64 + mi * 16 + quad * 4 + r;
                if (m < rows) {
                    float v = acc[mi][ni][r] + bias;
                    h_buf[(size_t)(sbase + m) * HID + n] = f2bf(gelu_exact(v));
                }
            }
        }
    }
}

// ---------------------------------------------------------------------------
// FFN2 (MFMA): y = x + (h @ W2t^T + b2) * top_val, scattered to token order.
// h: [4096][HID] bf16 sorted. W2t: [E][DIM][HID] bf16. out fp32 [T][DIM].
// ---------------------------------------------------------------------------
__global__ __launch_bounds__(256) void ffn2_mfma(
    const u16* __restrict__ h_buf, const u16* __restrict__ w2t,
    const float* __restrict__ b2, const float* __restrict__ x,
    const int* __restrict__ sorted_tok, const float* __restrict__ top_val,
    const int* __restrict__ tile_e, const int* __restrict__ tile_s,
    const int* __restrict__ tile_rows, const int* __restrict__ ntiles,
    float* __restrict__ yout)
{
    const int tile = blockIdx.x;
    if (tile >= *ntiles) return;
    const int e     = tile_e[tile];
    const int sbase = tile_s[tile];
    const int rows  = tile_rows[tile];
    const int nbase = blockIdx.y * TM;    // over DIM

    __shared__ __align__(16) u16 As[TM * BK];
    __shared__ __align__(16) u16 Bs[TM * BK];

    const int th = threadIdx.x;
    const int w  = th >> 6;
    const int l  = th & 63;
    const int wm = w >> 1, wn = w & 1;
    const int lr = l >> 3;
    const int lc = (l & 7) * 8;

    f32x4 acc[4][4] = {};

    const u16* wbase = w2t + (size_t)e * DIM * HID + (size_t)nbase * HID;

    for (int k0 = 0; k0 < HID; k0 += BK) {
        __syncthreads();
        #pragma unroll
        for (int c = 0; c < 4; c++) {
            const int r = w * 32 + c * 8;
            int srow = sbase + r + lr; if (srow > T_TOK - 1) srow = T_TOK - 1;
            gld_lds16(h_buf + (size_t)srow * HID + k0 + lc, &As[r * BK]);
        }
        #pragma unroll
        for (int c = 0; c < 4; c++) {
            const int r = w * 32 + c * 8;
            gld_lds16(wbase + (size_t)(r + lr) * HID + k0 + lc, &Bs[r * BK]);
        }
        __syncthreads();
        #pragma unroll
        for (int ks = 0; ks < 2; ks++) {
            const int ko = ks * 32 + (l >> 4) * 8;
            bf16x8 af[4], bfr[4];
            #pragma unroll
            for (int i = 0; i < 4; i++) {
                af[i]  = *(const bf16x8*)&As[(wm * 64 + i * 16 + (l & 15)) * BK + ko];
                bfr[i] = *(const bf16x8*)&Bs[(wn * 64 + i * 16 + (l & 15)) * BK + ko];
            }
            #pragma unroll
            for (int mi = 0; mi < 4; mi++)
                #pragma unroll
                for (int ni = 0; ni < 4; ni++)
                    acc[mi][ni] = __builtin_amdgcn_mfma_f32_16x16x32_bf16(
                        af[mi], bfr[ni], acc[mi][ni], 0, 0, 0);
        }
    }

    const int col = l & 15, quad = l >> 4;
    float bias[4];
    #pragma unroll
    for (int ni = 0; ni < 4; ni++)
        bias[ni] = b2[e * DIM + nbase + wn * 64 + ni * 16 + col];

    #pragma unroll
    for (int mi = 0; mi < 4; mi++) {
        #pragma unroll
        for (int r = 0; r < 4; r++) {
            const int m = wm * 64 + mi * 16 + quad * 4 + r;
            if (m < rows) {
                const int t = sorted_tok[sbase + m];
                const float tv = top_val[t];
                #pragma unroll
                for (int ni = 0; ni < 4; ni++) {
                    const int n = nbase + wn * 64 + ni * 16 + col;
                    float v = acc[mi][ni][r] + bias[ni];
                    yout[(size_t)t * DIM + n] = x[(size_t)t * DIM + n] + v * tv;
                }
            }
        }
    }
}

// ---------------------------------------------------------------------------
// RMSNorm (F.normalize * gamma * sqrt(D)) + exact GeLU, in place.
// ---------------------------------------------------------------------------
__global__ __launch_bounds__(256) void norm_kernel(float* __restrict__ y,
                                                   const float* __restrict__ gamma)
{
    const int t = blockIdx.x;
    float* row = y + (size_t)t * DIM;
    const int th = threadIdx.x;
    float4 v = *(const float4*)&row[th * 4];
    float ss = v.x * v.x + v.y * v.y + v.z * v.z + v.w * v.w;

    const int lane = th & 63, wave = th >> 6;
    #pragma unroll
    for (int off = 32; off > 0; off >>= 1) ss += __shfl_down(ss, off, 64);
    __shared__ float red[4];
    if (lane == 0) red[wave] = ss;
    __syncthreads();
    float total = red[0] + red[1] + red[2] + red[3];

    float nrm = sqrtf(total);
    float scale = 32.0f / fmaxf(nrm, 1e-12f);   // sqrt(1024) = 32

    float4 g = *(const float4*)&gamma[th * 4];
    float4 o;
    o.x = gelu_exact(v.x * scale * g.x);
    o.y = gelu_exact(v.y * scale * g.y);
    o.z = gelu_exact(v.z * scale * g.z);
    o.w = gelu_exact(v.w * scale * g.w);
    *(float4*)&row[th * 4] = o;
}

// ---------------------------------------------------------------------------
extern "C" void kernel_launch(void* const* d_in, const int* in_sizes, int n_in,
                              void* d_out, int out_size, void* d_ws, size_t ws_size,
                              hipStream_t stream) {
    const float* x      = (const float*)d_in[0];
    const float* gate_w = (const float*)d_in[1];
    const float* gate_b = (const float*)d_in[2];
    const float* w1     = (const float*)d_in[3];
    const float* b1     = (const float*)d_in[4];
    const float* w2     = (const float*)d_in[5];
    const float* b2     = (const float*)d_in[6];
    const float* gamma  = (const float*)d_in[7];

    float* out  = (float*)d_out;                  // [T*D] y, then [1] loss
    float* loss = out + (size_t)T_TOK * DIM;

    char* ws = (char*)d_ws;
    float* top_val    = (float*)(ws + 0);         // 4096 f
    int*   top_idx    = (int*)  (ws + 16384);     // 4096 i
    int*   sorted_tok = (int*)  (ws + 32768);     // 4096 i
    float* importance = (float*)(ws + 49152);     // 8 f  (zeroed)
    int*   counts     = (int*)  (ws + 49184);     // 8 i  (zeroed)
    int*   cursors    = (int*)  (ws + 49216);     // 8 i  (zeroed)
    int*   offsets    = (int*)  (ws + 49248);     // 9 i
    int*   tile_e     = (int*)  (ws + 49536);     // 40 i
    int*   tile_s     = (int*)  (ws + 49824);     // 40 i
    int*   tile_rows  = (int*)  (ws + 50112);     // 40 i
    int*   ntiles     = (int*)  (ws + 50400);     // 1 i
    u16*   x_sorted   = (u16*)  (ws + 65536);                    // 8 MiB
    u16*   h_buf      = (u16*)  (ws + 65536 + 8388608);          // 16 MiB
    u16*   w1t        = (u16*)  (ws + 65536 + 8388608 + 16777216);          // 32 MiB
    u16*   w2t        = (u16*)  (ws + 65536 + 8388608 + 16777216 + 33554432); // 32 MiB

    hipMemsetAsync(ws + 49152, 0, 96, stream);

    gate_kernel<<<T_TOK / 4, 256, 0, stream>>>(x, gate_w, gate_b, top_val,
                                               top_idx, importance, counts);
    plan_kernel<<<1, 64, 0, stream>>>(counts, importance, offsets, tile_e,
                                      tile_s, tile_rows, ntiles, loss);
    scatter_kernel<<<T_TOK / 256, 256, 0, stream>>>(top_idx, offsets, cursors,
                                                    sorted_tok);
    gather_x_kernel<<<T_TOK, 256, 0, stream>>>(x, sorted_tok, x_sorted);
    // w1 [E][D][H] -> w1t [E][H][D]
    transpose_bf16_kernel<<<dim3(HID / 32, DIM / 32, NE), 256, 0, stream>>>(
        w1, w1t, DIM, HID);
    // w2 [E][H][D] -> w2t [E][D][H]
    transpose_bf16_kernel<<<dim3(DIM / 32, HID / 32, NE), 256, 0, stream>>>(
        w2, w2t, HID, DIM);

    ffn1_mfma<<<dim3(40, HID / TM), 256, 0, stream>>>(
        x_sorted, w1t, b1, tile_e, tile_s, tile_rows, ntiles, h_buf);
    ffn2_mfma<<<dim3(40, DIM / TM), 256, 0, stream>>>(
        h_buf, w2t, b2, x, sorted_tok, top_val, tile_e, tile_s, tile_rows,
        ntiles, out);
    norm_kernel<<<T_TOK, 256, 0, stream>>>(out, gamma);
}